// Round 1
// baseline (972.331 us; speedup 1.0000x reference)
//
#include <hip/hip_runtime.h>
#include <hip/hip_bf16.h>
#include <stdint.h>

#define NN 100000
#define NE 1000000
#define DIM 128
#define NLAB 2048

typedef __attribute__((ext_vector_type(8))) short bf16x8;
typedef __attribute__((ext_vector_type(4))) float f32x4;
typedef __attribute__((ext_vector_type(2))) unsigned short us2;
typedef __attribute__((ext_vector_type(4))) unsigned short us4;

__device__ __forceinline__ unsigned short f2bf(float f){
    union { float f; unsigned int u; } v; v.f = f;
    unsigned int r = v.u + 0x7FFFu + ((v.u >> 16) & 1u);   // round-to-nearest-even
    return (unsigned short)(r >> 16);
}
__device__ __forceinline__ float bf2f(unsigned short b){
    union { unsigned int u; float f; } v; v.u = ((unsigned int)b) << 16;
    return v.f;
}

// ---------- CSR build ----------
__global__ void k_init(int* __restrict__ cnt, float* __restrict__ deg){
    int i = blockIdx.x*256 + threadIdx.x;
    if(i < NN){ cnt[i] = 0; deg[i] = 1.0f; }   // self-loop weight 1
}

__global__ void k_count(const int* __restrict__ col, const float* __restrict__ ew,
                        int* __restrict__ cnt, float* __restrict__ deg){
    int e = blockIdx.x*256 + threadIdx.x;
    if(e < NE){
        int c = col[e];
        atomicAdd(&cnt[c], 1);
        atomicAdd(&deg[c], ew[e]);
    }
}

__global__ void k_scan1(const int* __restrict__ cnt, int* __restrict__ excl,
                        int* __restrict__ bsum){
    __shared__ int s[256];
    int tid = threadIdx.x;
    int i = blockIdx.x*256 + tid;
    int v = (i < NN) ? cnt[i] : 0;
    int x = v;
    s[tid] = x; __syncthreads();
    for(int off=1; off<256; off<<=1){
        int t = (tid >= off) ? s[tid-off] : 0;
        __syncthreads();
        x += t; s[tid] = x;
        __syncthreads();
    }
    if(i < NN) excl[i] = x - v;
    if(tid == 255) bsum[blockIdx.x] = x;
}

__global__ void k_scan2(const int* __restrict__ bsum, int* __restrict__ bsumx, int nb){
    __shared__ int s[512];
    int tid = threadIdx.x;
    int v = (tid < nb) ? bsum[tid] : 0;
    int x = v;
    s[tid] = x; __syncthreads();
    for(int off=1; off<512; off<<=1){
        int t = (tid >= off) ? s[tid-off] : 0;
        __syncthreads();
        x += t; s[tid] = x;
        __syncthreads();
    }
    if(tid < nb) bsumx[tid] = x - v;
}

__global__ void k_scan3(const int* __restrict__ excl, const int* __restrict__ bsumx,
                        int* __restrict__ start, int* __restrict__ cursor){
    int i = blockIdx.x*256 + threadIdx.x;
    if(i < NN){
        int v = excl[i] + bsumx[blockIdx.x];
        start[i] = v; cursor[i] = v;
    }
    if(i == 0) start[NN] = NE;
}

__global__ void k_dinv(const float* __restrict__ deg, float* __restrict__ dinv){
    int i = blockIdx.x*256 + threadIdx.x;
    if(i < NN){ float d = deg[i]; dinv[i] = d > 0.f ? rsqrtf(d) : 0.f; }
}

__global__ void k_fill(const int* __restrict__ row, const int* __restrict__ col,
                       const float* __restrict__ ew, int* __restrict__ cursor,
                       int* __restrict__ csrc, float* __restrict__ cw){
    int e = blockIdx.x*256 + threadIdx.x;
    if(e < NE){
        int c = col[e];
        int p = atomicAdd(&cursor[c], 1);
        csrc[p] = row[e];
        cw[p]   = ew[e];
    }
}

// ---------- gather + fp32 -> bf16 ----------
__global__ void k_gather(const int* __restrict__ ni, const float* __restrict__ emb,
                         unsigned short* __restrict__ xbf){
    int id = blockIdx.x*256 + threadIdx.x;      // NN*32 threads, 4 elems each
    if(id >= NN*32) return;
    int i = id >> 5, q = (id & 31) << 2;
    float4 v = *reinterpret_cast<const float4*>(&emb[(long)ni[i]*DIM + q]);
    us4 o; o.x = f2bf(v.x); o.y = f2bf(v.y); o.z = f2bf(v.z); o.w = f2bf(v.w);
    *reinterpret_cast<us4*>(&xbf[(long)i*DIM + q]) = o;
}

// ---------- H = X @ W  (NNx128 @ 128x128, bf16 in, bf16 out) ----------
__global__ __launch_bounds__(256) void k_gemm128(const unsigned short* __restrict__ X,
                                                 const float* __restrict__ W,
                                                 unsigned short* __restrict__ H){
    __shared__ unsigned short Wt[DIM][DIM+8];   // [col][k], padded: conflict-free b128 reads
    int tid = threadIdx.x;
    #pragma unroll
    for(int t=0; t<64; ++t){
        int idx = tid + t*256;                  // 16384 elems
        int k = idx >> 7, j = idx & 127;
        Wt[j][k] = f2bf(W[k*DIM + j]);
    }
    __syncthreads();

    int lane = tid & 63, w = tid >> 6;
    int rowbase = blockIdx.x*64 + w*16;
    int r16 = lane & 15, ksel = lane >> 4;
    int arow = rowbase + r16; if(arow > NN-1) arow = NN-1;
    const unsigned short* xr = X + (long)arow*DIM;
    bf16x8 a[4];
    #pragma unroll
    for(int ks=0; ks<4; ++ks)
        a[ks] = *reinterpret_cast<const bf16x8*>(&xr[ks*32 + ksel*8]);

    f32x4 acc[8] = {};
    #pragma unroll
    for(int ks=0; ks<4; ++ks){
        #pragma unroll
        for(int nt=0; nt<8; ++nt){
            bf16x8 b = *reinterpret_cast<const bf16x8*>(&Wt[nt*16 + r16][ks*32 + ksel*8]);
            acc[nt] = __builtin_amdgcn_mfma_f32_16x16x32_bf16(a[ks], b, acc[nt], 0, 0, 0);
        }
    }

    int orow0 = rowbase + ksel*4;
    #pragma unroll
    for(int nt=0; nt<8; ++nt){
        int oc = nt*16 + r16;
        #pragma unroll
        for(int r=0; r<4; ++r){
            int orow = orow0 + r;
            if(orow < NN) H[(long)orow*DIM + oc] = f2bf(acc[nt][r]);
        }
    }
}

// ---------- fused aggregation: X_out = relu( dinv_c*(sum_e w*dinv_r*H[r] + dinv_c*H[c]) + b ) ----------
__global__ void k_agg(const unsigned short* __restrict__ H, const int* __restrict__ start,
                      const int* __restrict__ csrc, const float* __restrict__ cw,
                      const float* __restrict__ dinv, const float* __restrict__ bias,
                      unsigned short* __restrict__ Xo){
    int wid  = (blockIdx.x*256 + threadIdx.x) >> 6;   // one wave per node
    int lane = threadIdx.x & 63;
    if(wid >= NN) return;
    int c = wid;
    int d2 = lane*2;
    float acc0 = 0.f, acc1 = 0.f;
    int s = start[c], e = start[c+1];
    float dc = dinv[c];
    for(int p=s; p<e; ++p){
        int r    = csrc[p];
        float sc = cw[p] * dinv[r];
        us2 hv = *reinterpret_cast<const us2*>(&H[(long)r*DIM + d2]);
        acc0 += sc * bf2f(hv.x);
        acc1 += sc * bf2f(hv.y);
    }
    us2 hc = *reinterpret_cast<const us2*>(&H[(long)c*DIM + d2]);
    acc0 = dc*(acc0 + dc*bf2f(hc.x)) + bias[d2];
    acc1 = dc*(acc1 + dc*bf2f(hc.y)) + bias[d2+1];
    acc0 = acc0 > 0.f ? acc0 : 0.f;
    acc1 = acc1 > 0.f ? acc1 : 0.f;
    us2 o; o.x = f2bf(acc0); o.y = f2bf(acc1);
    *reinterpret_cast<us2*>(&Xo[(long)c*DIM + d2]) = o;
}

// ---------- out = X @ Wout + bout  (NNx128 @ 128x2048, fp32 out) ----------
__global__ __launch_bounds__(256) void k_gemm_out(const unsigned short* __restrict__ X,
                                                  const float* __restrict__ Wout,
                                                  const float* __restrict__ bout,
                                                  float* __restrict__ out){
    extern __shared__ unsigned short Bt[];      // [256][DIM+8] = 69632 B
    const int LDB = DIM + 8;
    int bid = blockIdx.x;
    int rowg = bid >> 3, colg = bid & 7;
    int colbase = colg * 256;
    int tid = threadIdx.x;
    #pragma unroll
    for(int t=0; t<128; ++t){
        int idx = tid + t*256;                  // 32768 elems
        int k = idx >> 8, cc = idx & 255;
        Bt[cc*LDB + k] = f2bf(Wout[(long)k*NLAB + colbase + cc]);
    }
    __syncthreads();

    int lane = tid & 63, w = tid >> 6;
    int rowbase = rowg*64 + w*16;
    int r16 = lane & 15, ksel = lane >> 4;
    int arow = rowbase + r16; if(arow > NN-1) arow = NN-1;
    const unsigned short* xr = X + (long)arow*DIM;
    bf16x8 a[4];
    #pragma unroll
    for(int ks=0; ks<4; ++ks)
        a[ks] = *reinterpret_cast<const bf16x8*>(&xr[ks*32 + ksel*8]);

    f32x4 acc[16] = {};
    #pragma unroll
    for(int ks=0; ks<4; ++ks){
        #pragma unroll
        for(int nt=0; nt<16; ++nt){
            bf16x8 b = *reinterpret_cast<const bf16x8*>(&Bt[(nt*16 + r16)*LDB + ks*32 + ksel*8]);
            acc[nt] = __builtin_amdgcn_mfma_f32_16x16x32_bf16(a[ks], b, acc[nt], 0, 0, 0);
        }
    }

    int orow0 = rowbase + ksel*4;
    #pragma unroll
    for(int nt=0; nt<16; ++nt){
        int oc = colbase + nt*16 + r16;
        float bv = bout[oc];
        #pragma unroll
        for(int r=0; r<4; ++r){
            int orow = orow0 + r;
            if(orow < NN) out[(long)orow*NLAB + oc] = acc[nt][r] + bv;
        }
    }
}

extern "C" void kernel_launch(void* const* d_in, const int* in_sizes, int n_in,
                              void* d_out, int out_size, void* d_ws, size_t ws_size,
                              hipStream_t stream){
    const int*   ni  = (const int*)  d_in[0];
    const int*   ei  = (const int*)  d_in[1];
    const float* ew  = (const float*)d_in[2];
    const float* emb = (const float*)d_in[3];
    const float* W1  = (const float*)d_in[4];
    const float* b1  = (const float*)d_in[5];
    const float* W2  = (const float*)d_in[6];
    const float* b2  = (const float*)d_in[7];
    const float* Wo  = (const float*)d_in[8];
    const float* bo  = (const float*)d_in[9];
    float* out = (float*)d_out;
    const int* row = ei;
    const int* col = ei + NE;

    char* ws = (char*)d_ws;
    size_t off = 0;
    auto alloc = [&](size_t bytes){ void* p = ws + off; off += (bytes + 255) & ~size_t(255); return p; };
    int*   cnt    = (int*)  alloc((size_t)NN*4);
    int*   excl   = (int*)  alloc((size_t)NN*4);
    int*   bsum   = (int*)  alloc(512*4);
    int*   bsumx  = (int*)  alloc(512*4);
    int*   start  = (int*)  alloc((size_t)(NN+1)*4);
    int*   cursor = (int*)  alloc((size_t)NN*4);
    float* deg    = (float*)alloc((size_t)NN*4);
    float* dinv   = (float*)alloc((size_t)NN*4);
    int*   csrc   = (int*)  alloc((size_t)NE*4);
    float* cw     = (float*)alloc((size_t)NE*4);
    unsigned short* Xbf = (unsigned short*)alloc((size_t)NN*DIM*2);
    unsigned short* Hbf = (unsigned short*)alloc((size_t)NN*DIM*2);

    const int nbN = (NN + 255)/256;             // 391
    const int nbE = (NE + 255)/256;             // 3907

    k_init <<<nbN, 256, 0, stream>>>(cnt, deg);
    k_count<<<nbE, 256, 0, stream>>>(col, ew, cnt, deg);
    k_scan1<<<nbN, 256, 0, stream>>>(cnt, excl, bsum);
    k_scan2<<<1,   512, 0, stream>>>(bsum, bsumx, nbN);
    k_scan3<<<nbN, 256, 0, stream>>>(excl, bsumx, start, cursor);
    k_dinv <<<nbN, 256, 0, stream>>>(deg, dinv);
    k_fill <<<nbE, 256, 0, stream>>>(row, col, ew, cursor, csrc, cw);

    k_gather<<<(NN*32 + 255)/256, 256, 0, stream>>>(ni, emb, Xbf);

    // layer 1
    k_gemm128<<<(NN+63)/64, 256, 0, stream>>>(Xbf, W1, Hbf);
    k_agg    <<<(NN*64+255)/256, 256, 0, stream>>>(Hbf, start, csrc, cw, dinv, b1, Xbf);
    // layer 2
    k_gemm128<<<(NN+63)/64, 256, 0, stream>>>(Xbf, W2, Hbf);
    k_agg    <<<(NN*64+255)/256, 256, 0, stream>>>(Hbf, start, csrc, cw, dinv, b2, Xbf);
    // output projection
    k_gemm_out<<<((NN+63)/64)*8, 256, 69632, stream>>>(Xbf, Wo, bo, out);
}